// Round 1
// baseline (1026.058 us; speedup 1.0000x reference)
//
#include <hip/hip_runtime.h>
#include <math.h>

// AngularLayer: out[B,483] = concat(in[B,63], tilts[B,420])
// tilts: for each pair (i<k) of 21 landmarks (x,y at cols 3i,3i+1):
//   v = p_k - p_i; tilt = clip(v/||v||, -1, 1), (x,y) per pair at cols 63+2p.
//
// Memory-bound: 126 MB read + 966 MB write -> ~173 us floor @ 6.3 TB/s.
// V2 structure: 64-row slab per block (1024 thr = 16 waves), lane = row.
//   - Pair indices are wave-uniform; switch(wave) -> fully unrolled template
//     chain makes every LDS offset an immediate (no index tables, no
//     dependent LDS chains). Landmarks live in 42 regs/lane.
//   - s_in stride 63 (== -1 mod 32) and s_out stride 483 (== 3 mod 32)
//     are conflict-free across 64 lanes.
//   - Grid-stride persistent blocks (1 block/CU) with double-buffered input:
//     next slab's float4 loads issued BEFORE compute (latency hidden),
//     ds_write'd to the spare buffer after the dump.
//   - 152 KB dynamic LDS (opt-in). If the opt-in fails, fall back to the
//     proven 16-row static-LDS kernel.

#define NCOLS    63
#define OUTCOLS  483
#define NPAIRS   210
#define SROWS    64
#define BLOCK    1024
#define GRIDB    256

#define IN_SLAB_F4   ((SROWS * NCOLS) / 4)                  // 1008 float4
#define OUT_SLAB_F   (SROWS * OUTCOLS)                      // 30912 floats
#define SMEM_FLOATS  (OUT_SLAB_F + 2 * SROWS * NCOLS)       // 38976 -> 155904 B

constexpr int pair_i(int p) {
    int i = 0, off = 0;
    while (off + (20 - i) <= p) { off += 20 - i; ++i; }
    return i;
}
constexpr int pair_k(int p) {
    int i = 0, off = 0;
    while (off + (20 - i) <= p) { off += 20 - i; ++i; }
    return i + 1 + (p - off);
}

template<int P, int PEND>
struct PairChain {
    static __device__ __forceinline__ void run(const float (&lm)[42],
                                               float* __restrict__ rowout) {
        constexpr int i = pair_i(P);
        constexpr int k = pair_k(P);
        const float vx = lm[2 * k]     - lm[2 * i];
        const float vy = lm[2 * k + 1] - lm[2 * i + 1];
        const float inv = rsqrtf(vx * vx + vy * vy);
        float tx = fminf(fmaxf(vx * inv, -1.0f), 1.0f);
        float ty = fminf(fmaxf(vy * inv, -1.0f), 1.0f);
        rowout[NCOLS + 2 * P]     = tx;   // immediate LDS offsets
        rowout[NCOLS + 2 * P + 1] = ty;
        PairChain<P + 1, PEND>::run(lm, rowout);
    }
};
template<int PEND>
struct PairChain<PEND, PEND> {
    static __device__ __forceinline__ void run(const float (&)[42],
                                               float* __restrict__) {}
};

template<int W>
__device__ __forceinline__ void wave_compute(const float* __restrict__ rowin,
                                             float* __restrict__ rowout) {
    // passthrough columns [4W, 4W+4) clipped to 63
    constexpr int C0 = 4 * W;
    constexpr int C1 = (4 * W + 4 < NCOLS) ? (4 * W + 4) : NCOLS;
#pragma unroll
    for (int c = C0; c < C1; ++c) rowout[c] = rowin[c];

    // landmark (x,y) -> registers; unused entries are DCE'd per wave
    float lm[42];
#pragma unroll
    for (int i = 0; i < 21; ++i) {
        lm[2 * i]     = rowin[3 * i];
        lm[2 * i + 1] = rowin[3 * i + 1];
    }
    // pair partition: waves 0,1 get 14 pairs; waves 2..15 get 13 (= 210)
    constexpr int P0 = (W < 2) ? 14 * W : 28 + 13 * (W - 2);
    constexpr int P1 = (W < 2) ? P0 + 14 : P0 + 13;
    PairChain<P0, P1>::run(lm, rowout);
}

__global__ __launch_bounds__(BLOCK) void angular_slab_kernel(
    const float* __restrict__ in, float* __restrict__ out, int B, int nslab) {
    extern __shared__ float smem[];
    float* s_out = smem;                                 // 30912 floats
    float* s_inA = smem + OUT_SLAB_F;                    // 4032 floats
    float* s_inB = s_inA + SROWS * NCOLS;                // 4032 floats

    const int t = threadIdx.x;
    const int w = t >> 6;
    const int l = t & 63;
    const size_t total_in4 = ((size_t)B * NCOLS) >> 2;
    const float4* __restrict__ gin4 = (const float4*)in;

    // ---- prologue: stage first slab into A ----
    const size_t slab0 = blockIdx.x;
    if (t < IN_SLAB_F4) {
        const size_t g = slab0 * IN_SLAB_F4 + (size_t)t;
        float4 r = make_float4(0.f, 0.f, 0.f, 0.f);
        if (g < total_in4) r = gin4[g];
        ((float4*)s_inA)[t] = r;
    }
    __syncthreads();

    int cur = 0;
    for (size_t slab = slab0; slab < (size_t)nslab; slab += gridDim.x) {
        // ---- issue next slab's loads early (latency hides under compute) ----
        const size_t nxt = slab + gridDim.x;
        const bool havenxt = nxt < (size_t)nslab;
        float4 r = make_float4(0.f, 0.f, 0.f, 0.f);
        if (havenxt && t < IN_SLAB_F4) {
            const size_t g = nxt * IN_SLAB_F4 + (size_t)t;
            if (g < total_in4) r = gin4[g];
        }

        // ---- compute: lane = row, wave-uniform compile-time pair list ----
        {
            const float* __restrict__ s_cur = cur ? s_inB : s_inA;
            const float* __restrict__ rowin = s_cur + l * NCOLS;
            float* __restrict__ rowout = s_out + l * OUTCOLS;
            switch (w) {
                case 0:  wave_compute<0>(rowin, rowout);  break;
                case 1:  wave_compute<1>(rowin, rowout);  break;
                case 2:  wave_compute<2>(rowin, rowout);  break;
                case 3:  wave_compute<3>(rowin, rowout);  break;
                case 4:  wave_compute<4>(rowin, rowout);  break;
                case 5:  wave_compute<5>(rowin, rowout);  break;
                case 6:  wave_compute<6>(rowin, rowout);  break;
                case 7:  wave_compute<7>(rowin, rowout);  break;
                case 8:  wave_compute<8>(rowin, rowout);  break;
                case 9:  wave_compute<9>(rowin, rowout);  break;
                case 10: wave_compute<10>(rowin, rowout); break;
                case 11: wave_compute<11>(rowin, rowout); break;
                case 12: wave_compute<12>(rowin, rowout); break;
                case 13: wave_compute<13>(rowin, rowout); break;
                case 14: wave_compute<14>(rowin, rowout); break;
                default: wave_compute<15>(rowin, rowout); break;
            }
        }
        __syncthreads();

        // ---- dump: whole slab contiguous, 16B-aligned float4 stream ----
        {
            const size_t row0 = slab * SROWS;
            const size_t rows = ((size_t)B - row0 >= SROWS) ? SROWS
                                                            : ((size_t)B - row0);
            float4* __restrict__ gout4 = (float4*)(out + row0 * OUTCOLS);
            const float4* s_out4 = (const float4*)s_out;
            const int lim4 = (int)((rows * OUTCOLS) >> 2);
            for (int idx = t; idx < lim4; idx += BLOCK)
                gout4[idx] = s_out4[idx];
            const int rem = (int)((rows * OUTCOLS) & 3);   // 0 for even row counts
            if (rem && t < rem)
                out[row0 * OUTCOLS + (size_t)lim4 * 4 + t] = s_out[lim4 * 4 + t];
        }

        // ---- land prefetched input into the spare buffer ----
        if (havenxt && t < IN_SLAB_F4) {
            float* s_nxt = cur ? s_inA : s_inB;
            ((float4*)s_nxt)[t] = r;
        }
        __syncthreads();
        cur ^= 1;
    }
}

// ---------------- fallback: previous proven 16-row kernel ----------------
#define FROWS 16
#define FBLOCK 256

__global__ __launch_bounds__(FBLOCK) void angular_kernel_small(
    const float* __restrict__ in, float* __restrict__ out, int B) {
    __shared__ float s_in[FROWS * NCOLS];
    __shared__ float s_out[FROWS * OUTCOLS];
    __shared__ int   s_pi[NPAIRS];
    __shared__ int   s_pk[NPAIRS];

    const int t = threadIdx.x;
    if (t < NPAIRS) {
        int p = t, i = 0, off = 0;
        while (off + (20 - i) <= p) { off += 20 - i; ++i; }
        s_pi[t] = 3 * i;
        s_pk[t] = 3 * (i + 1 + (p - off));
    }
    const size_t row0 = (size_t)blockIdx.x * FROWS;
    const bool full = (row0 + FROWS) <= (size_t)B;
    if (full) {
        const float4* gin4 = (const float4*)(in + row0 * NCOLS);
        float4* s_in4 = (float4*)s_in;
        if (t < (FROWS * NCOLS) / 4) s_in4[t] = gin4[t];
    } else {
        for (int idx = t; idx < FROWS * NCOLS; idx += FBLOCK) {
            size_t g = row0 * NCOLS + (size_t)idx;
            if (g < (size_t)B * NCOLS) s_in[idx] = in[g];
        }
    }
    __syncthreads();
    const int r = t >> 4;
    const int l = t & 15;
    const float* rowin  = s_in  + r * NCOLS;
    float*       rowout = s_out + r * OUTCOLS;
    for (int c = l; c < NCOLS; c += 16) rowout[c] = rowin[c];
    for (int p = l; p < NPAIRS; p += 16) {
        const int ia = s_pi[p], ka = s_pk[p];
        const float vx = rowin[ka]     - rowin[ia];
        const float vy = rowin[ka + 1] - rowin[ia + 1];
        const float inv = rsqrtf(vx * vx + vy * vy);
        float tx = fminf(fmaxf(vx * inv, -1.0f), 1.0f);
        float ty = fminf(fmaxf(vy * inv, -1.0f), 1.0f);
        rowout[NCOLS + 2 * p]     = tx;
        rowout[NCOLS + 2 * p + 1] = ty;
    }
    __syncthreads();
    if (full) {
        float4* gout4 = (float4*)(out + row0 * OUTCOLS);
        const float4* s_out4 = (const float4*)s_out;
        for (int idx = t; idx < (FROWS * OUTCOLS) / 4; idx += FBLOCK)
            gout4[idx] = s_out4[idx];
    } else {
        for (int idx = t; idx < FROWS * OUTCOLS; idx += FBLOCK) {
            size_t g = row0 * OUTCOLS + (size_t)idx;
            if (g < (size_t)B * OUTCOLS) out[g] = s_out[idx];
        }
    }
}

extern "C" void kernel_launch(void* const* d_in, const int* in_sizes, int n_in,
                              void* d_out, int out_size, void* d_ws, size_t ws_size,
                              hipStream_t stream) {
    const float* in = (const float*)d_in[0];
    float* out = (float*)d_out;
    const int B = in_sizes[0] / NCOLS;
    const int nslab = (B + SROWS - 1) / SROWS;

    // One-time opt-in for 152 KB dynamic LDS (gfx950 has 160 KB/CU).
    static int use_big = -1;
    if (use_big < 0) {
        hipError_t e = hipFuncSetAttribute(
            reinterpret_cast<const void*>(&angular_slab_kernel),
            hipFuncAttributeMaxDynamicSharedMemorySize,
            (int)(SMEM_FLOATS * sizeof(float)));
        use_big = (e == hipSuccess) ? 1 : 0;
    }

    if (use_big) {
        int grid = GRIDB;
        if (grid > nslab) grid = nslab;
        hipLaunchKernelGGL(angular_slab_kernel, dim3(grid), dim3(BLOCK),
                           SMEM_FLOATS * sizeof(float), stream, in, out, B, nslab);
    } else {
        const int grid = (B + FROWS - 1) / FROWS;
        hipLaunchKernelGGL(angular_kernel_small, dim3(grid), dim3(FBLOCK), 0,
                           stream, in, out, B);
    }
}

// Round 3
// 1019.469 us; speedup vs baseline: 1.0065x; 1.0065x over previous
//
#include <hip/hip_runtime.h>
#include <math.h>

// AngularLayer: out[B,483] = concat(in[B,63], tilts[B,420])
// tilts: for each pair (i<k) of 21 landmarks (x,y at cols 3i,3i+1):
//   v = p_k - p_i; tilt = clip(v/||v||, -1, 1), (x,y) per pair at cols 63+2p.
//
// Memory-bound: 126 MB read + 966 MB write -> ~173 us floor @ 6.3 TB/s.
//
// V3 insight (post-mortem of V1/V2): both prior kernels staged the OUTPUT
// in LDS, costing ~5 LDS lane-ops per output float (compute reads + s_out
// write + dump read) = 20B LDS per 4B HBM. That co-saturates the LDS pipe
// with the store stream (both ~3000 cyc per 16-row slab per CU), and the
// barrier-phased structure serializes them -> ~2.7 TB/s effective.
//
// V3: NO s_out. Threads map directly onto the output float4 stream:
//   chunk q = 4 consecutive floats of the [rows x 483] slab (chunks may
//   straddle a row boundary; one div + carry handles it). Each float is
//   either a passthrough read from the LDS input tile or a pair feature
//   computed from 4 landmark reads + 1 packed-LUT read. Register float4
//   goes straight to global - perfectly coalesced, no second barrier,
//   no phase lockstep. LDS traffic per output float: ~2.5 lane-ops.
// Small footprint (9 KB LDS, 256 thr) -> 8 blocks/CU for cross-block TLP.
//
// (R2 run died with an infra error "container failed twice" before any
// kernel output; resubmitting with minor hardening, algorithm unchanged.)

#define NCOLS    63
#define OUTCOLS  483
#define NPAIRS   210
#define ROWS     32
#define BLOCK    256

#define IN_SLAB   (ROWS * NCOLS)        // 2016 floats
#define IN_SLAB4  (IN_SLAB / 4)         // 504 float4

__global__ __launch_bounds__(BLOCK) void angular_direct_kernel(
    const float* __restrict__ in, float* __restrict__ out, int B) {
    __shared__ float s_in[IN_SLAB];     // 8064 B
    __shared__ int   s_tab[NPAIRS];     // packed (3k << 16) | 3i, 840 B

    const int t = threadIdx.x;

    // Build packed pair LUT (once per block, trivial).
    if (t < NPAIRS) {
        int p = t, i = 0, off = 0;
#pragma unroll 1
        for (int it = 0; it < 20; ++it) {
            if (off + (20 - i) <= p) { off += 20 - i; ++i; } else break;
        }
        int k = i + 1 + (p - off);
        s_tab[t] = (3 * k << 16) | (3 * i);
    }

    const size_t row0 = (size_t)blockIdx.x * ROWS;
    if (row0 >= (size_t)B) return;      // defensive; grid is sized to B
    const int rows = ((size_t)B - row0 >= ROWS) ? ROWS : (int)((size_t)B - row0);

    // ---- Stage input tile (float4; slab base 32*63*4 = 8064B-aligned) ----
    if (rows == ROWS) {
        const float4* __restrict__ gin4 = (const float4*)(in + row0 * NCOLS);
        float4* s4 = (float4*)s_in;
#pragma unroll
        for (int j = 0; j < (IN_SLAB4 + BLOCK - 1) / BLOCK; ++j) {
            const int idx = t + j * BLOCK;
            if (idx < IN_SLAB4) s4[idx] = gin4[idx];
        }
    } else {
        for (int idx = t; idx < rows * NCOLS; idx += BLOCK)
            s_in[idx] = in[row0 * NCOLS + (size_t)idx];
    }
    __syncthreads();

    // ---- Direct compute + store over the output float4 stream ----
    // Slab float4 base: row0*483*4 bytes, row0 % 4 == 0 -> 16B aligned.
    const int nfloat = rows * OUTCOLS;
    const int nchunk = nfloat >> 2;
    float4* __restrict__ gout4 = (float4*)(out + row0 * OUTCOLS);

    for (int q = t; q < nchunk; q += BLOCK) {
        const int f0 = q << 2;
        const int r0 = f0 / OUTCOLS;          // magic-mul division
        const int c0 = f0 - r0 * OUTCOLS;
        float vals[4];
#pragma unroll
        for (int u = 0; u < 4; ++u) {
            int r = r0, c = c0 + u;
            if (c >= OUTCOLS) { ++r; c -= OUTCOLS; }   // at most one wrap
            const float* __restrict__ rowin = s_in + r * NCOLS;
            float v;
            if (c < NCOLS) {
                v = rowin[c];
            } else {
                const int idx = c - NCOLS;
                const int tab = s_tab[idx >> 1];
                const int ia = tab & 0xffff;           // 3i
                const int ka = tab >> 16;              // 3k
                const float vx = rowin[ka]     - rowin[ia];
                const float vy = rowin[ka + 1] - rowin[ia + 1];
                const float inv = rsqrtf(vx * vx + vy * vy);
                const float tv = ((idx & 1) ? vy : vx) * inv;
                v = fminf(fmaxf(tv, -1.0f), 1.0f);
            }
            vals[u] = v;
        }
        gout4[q] = make_float4(vals[0], vals[1], vals[2], vals[3]);
    }

    // Scalar tail (nfloat % 4 != 0 only when rows % 4 != 0; B=500000 -> never).
    const int rem = nfloat & 3;
    if (rem && t < rem) {
        const int fi = (nchunk << 2) + t;
        const int r = fi / OUTCOLS;
        const int c = fi - r * OUTCOLS;
        const float* __restrict__ rowin = s_in + r * NCOLS;
        float v;
        if (c < NCOLS) {
            v = rowin[c];
        } else {
            const int idx = c - NCOLS;
            const int tab = s_tab[idx >> 1];
            const int ia = tab & 0xffff;
            const int ka = tab >> 16;
            const float vx = rowin[ka]     - rowin[ia];
            const float vy = rowin[ka + 1] - rowin[ia + 1];
            const float inv = rsqrtf(vx * vx + vy * vy);
            const float tv = ((idx & 1) ? vy : vx) * inv;
            v = fminf(fmaxf(tv, -1.0f), 1.0f);
        }
        out[row0 * OUTCOLS + (size_t)fi] = v;
    }
}

extern "C" void kernel_launch(void* const* d_in, const int* in_sizes, int n_in,
                              void* d_out, int out_size, void* d_ws, size_t ws_size,
                              hipStream_t stream) {
    const float* in = (const float*)d_in[0];
    float* out = (float*)d_out;
    const int B = in_sizes[0] / NCOLS;
    if (B <= 0) return;
    const int grid = (B + ROWS - 1) / ROWS;
    hipLaunchKernelGGL(angular_direct_kernel, dim3(grid), dim3(BLOCK), 0,
                       stream, in, out, B);
}